// Round 13
// baseline (309.201 us; speedup 1.0000x reference)
//
#include <hip/hip_runtime.h>

// SLAM layer: out[1,T,M,E,1] = (main[T,M,K] @ relu(x_aux[K,T,Da] @ W[Da,E] + b)[K,T,E] per t)
// T=128, M=512, K=256, Da=256, E=512.
// R13 (= R8 resubmit; R8-R12 hit GPU-broker timeouts, never ran): main rebuilt
// BARRIER-FREE: per-wave private LDS double-buffer for x_main staging
// (global->reg->bf16->ds_write, 1-deep ahead), af (auxc chunks) 1-deep register prefetch,
// XOR-swizzled LDS writes (kills R7's 9.7M bank conflicts). No __syncthreads in main.
// aux/wchunk = R3 verified versions. xmchunk pass stays deleted.

typedef __attribute__((ext_vector_type(8))) short  bf16x8;   // MFMA A/B frag (4 VGPR)
typedef __attribute__((ext_vector_type(4))) float  f32x4;    // MFMA C/D frag
typedef __attribute__((ext_vector_type(4))) unsigned int uint4v;
typedef __attribute__((ext_vector_type(2))) unsigned int uint2v;

#define T_DIM 128
#define M_DIM 512
#define K_DIM 256
#define DA    256
#define DENSE 512
// auxc chunk layout (bf16): (t,k,e) -> t*131072 + (k>>3)*4096 + e*8 + (k&7)
#define CHUNK_T_STRIDE 131072
#define CHUNK_G_STRIDE 4096

__device__ __forceinline__ unsigned short f2bf(float f) {
    unsigned u = __builtin_bit_cast(unsigned, f);
    unsigned r = (u + 0x7fffu + ((u >> 16) & 1u)) >> 16;   // RNE
    return (unsigned short)r;
}
__device__ __forceinline__ unsigned pack2(float lo, float hi) {
    return (unsigned)f2bf(lo) | ((unsigned)f2bf(hi) << 16);
}

// ---------------- Kernel 0: W [Da][E] f32 -> Wc bf16 chunks [g][e][8] ----------------------
__global__ __launch_bounds__(256) void wchunk_kernel(const float* __restrict__ W,
                                                     unsigned short* __restrict__ Wc) {
    int c = blockIdx.x * 256 + threadIdx.x;   // chunk id = g*DENSE + e
    int g = c >> 9;
    int e = c & 511;
    float f[8];
#pragma unroll
    for (int j = 0; j < 8; ++j) f[j] = W[(g * 8 + j) * DENSE + e];
    uint4v w;
    w.x = pack2(f[0], f[1]); w.y = pack2(f[2], f[3]);
    w.z = pack2(f[4], f[5]); w.w = pack2(f[6], f[7]);
    *reinterpret_cast<uint4v*>(Wc + (size_t)c * 8) = w;
}

// ---------------- Kernel 1: aux GEMM (unchanged from R3, verified) -------------------------
__global__ __launch_bounds__(256) void aux_kernel(const float* __restrict__ xaux,
                                                  const unsigned short* __restrict__ Wc,
                                                  const float* __restrict__ bias,
                                                  unsigned short* __restrict__ auxc) {
    __shared__ unsigned short xa[64 * 264];   // 33792 B, 528B row stride
    const int bid = blockIdx.x;               // 1024 blocks
    const int swz = (bid & 7) * 128 + (bid >> 3);   // XCD-grouped, bijective
    const int t  = swz >> 3;
    const int r  = swz & 7;
    const int kb = (r >> 1) * 64;
    const int eb = (r & 1) * 256;
    const int tid = threadIdx.x, lane = tid & 63, wid = tid >> 6;
    const int l15 = lane & 15, lg = lane >> 4;
    char* xab = reinterpret_cast<char*>(xa);

#pragma unroll
    for (int j = 0; j < 16; ++j) {
        int kr = wid + 4 * j;
        const float* src = xaux + ((size_t)(kb + kr) * T_DIM + t) * DA + lane * 4;
        f32x4 v = *reinterpret_cast<const f32x4*>(src);
        uint2v o; o.x = pack2(v.x, v.y); o.y = pack2(v.z, v.w);
        *reinterpret_cast<uint2v*>(xab + kr * 528 + lane * 8) = o;
    }
    __syncthreads();

    const int we = wid * 64;
    f32x4 acc[4][4];
#pragma unroll
    for (int i = 0; i < 4; ++i)
#pragma unroll
        for (int j = 0; j < 4; ++j) acc[i][j] = (f32x4)0.0f;

#define AUX_LOAD_WF(dst, dsv)                                                              \
    do {                                                                                   \
        _Pragma("unroll") for (int j = 0; j < 4; ++j) {                                    \
            int e = eb + we + j * 16 + l15;                                                \
            dst[j] = *reinterpret_cast<const bf16x8*>(                                     \
                Wc + (size_t)((dsv) * 4 + lg) * CHUNK_G_STRIDE + (size_t)e * 8);           \
        }                                                                                  \
    } while (0)

#define AUX_COMPUTE(wfc, dsv)                                                              \
    do {                                                                                   \
        bf16x8 xf[4];                                                                      \
        _Pragma("unroll") for (int i = 0; i < 4; ++i)                                      \
            xf[i] = *reinterpret_cast<const bf16x8*>(                                      \
                xab + (i * 16 + l15) * 528 + ((dsv) * 4 + lg) * 16);                       \
        _Pragma("unroll") for (int i = 0; i < 4; ++i)                                      \
            _Pragma("unroll") for (int j = 0; j < 4; ++j)                                  \
                acc[i][j] = __builtin_amdgcn_mfma_f32_16x16x32_bf16(xf[i], wfc[j], acc[i][j], 0, 0, 0); \
    } while (0)

    bf16x8 wfA[4], wfB[4];
    AUX_LOAD_WF(wfA, 0);
#pragma unroll
    for (int ds = 0; ds < 8; ds += 2) {
        AUX_LOAD_WF(wfB, ds + 1);
        AUX_COMPUTE(wfA, ds);
        if (ds + 2 < 8) { AUX_LOAD_WF(wfA, ds + 2); }
        AUX_COMPUTE(wfB, ds + 1);
    }
#undef AUX_LOAD_WF
#undef AUX_COMPUTE

#pragma unroll
    for (int i = 0; i < 4; ++i) {
        int k0 = kb + i * 16 + lg * 4;        // 4 consecutive k; k0&7 in {0,4}
#pragma unroll
        for (int j = 0; j < 4; ++j) {
            int e = eb + we + j * 16 + l15;
            float bv = bias[e];
            float v0 = fmaxf(acc[i][j].x + bv, 0.0f);
            float v1 = fmaxf(acc[i][j].y + bv, 0.0f);
            float v2 = fmaxf(acc[i][j].z + bv, 0.0f);
            float v3 = fmaxf(acc[i][j].w + bv, 0.0f);
            uint2 o; o.x = pack2(v0, v1); o.y = pack2(v2, v3);
            size_t idx = (size_t)t * CHUNK_T_STRIDE + (size_t)(k0 >> 3) * CHUNK_G_STRIDE
                       + (size_t)e * 8 + (k0 & 7);
            *reinterpret_cast<uint2*>(auxc + idx) = o;
        }
    }
}

// ---------------- Kernel 2: main GEMM v6 (barrier-free, per-wave LDS dbuf) -----------------
// D[e][m] = sum_k auxc[k][e] * x_main[t][m][k]. Each wave owns 64m x 64e output tile,
// stages its own 64m x 32k x_main sub-tile into a PRIVATE LDS double-buffer.
// Per-wave LDS buf layout: [g=k/8:4][m:64][16B], byte XOR ^(g<<4) (write 2-way, read 2-way).
__global__ __launch_bounds__(256, 3) void main_kernel(const float* __restrict__ xmain,
                                                      const unsigned short* __restrict__ auxc,
                                                      float* __restrict__ out) {
    __shared__ char mlds[32768];                     // 4 waves x 2 bufs x 4KB
    const int bid = blockIdx.x;                      // 2048 blocks
    const int swz = ((bid & 7) << 8) | (bid >> 3);   // XCD-grouped, bijective
    const int t   = swz >> 4;
    const int r4  = swz & 15;
    const int eb  = (r4 & 3) * 128;
    const int mb  = (r4 >> 2) * 128;
    const int lane = threadIdx.x & 63, wid = threadIdx.x >> 6;
    const int wm = (wid & 1) * 64;
    const int we = (wid >> 1) * 64;
    const int l15 = lane & 15, lg = lane >> 4;
    // staging lane coords: 8 rows x 8 k-quads per gload pass
    const int sr = lane >> 3;                        // row-in-octet 0..7
    const int sk = lane & 7;                         // k-quad 0..7 (4 floats each)
    const int sg = sk >> 1, sh = sk & 1;             // k-octet (LDS g), half

    char* const wbase = mlds + wid * 8192;           // private: 2 bufs x 4096B
    const float* Atw = xmain + (size_t)t * (M_DIM * K_DIM) + (size_t)(mb + wm) * K_DIM;
    const unsigned short* Ct = auxc + (size_t)t * CHUNK_T_STRIDE;

    f32x4 acc[4][4];
#pragma unroll
    for (int i = 0; i < 4; ++i)
#pragma unroll
        for (int j = 0; j < 4; ++j) acc[i][j] = (f32x4)0.0f;

    f32x4  ms[8];          // staging regs (1 set, fully unrolled indices)
    bf16x8 afr[2][4];      // af 1-deep prefetch

#define MF_GLOAD(ksv)                                                                      \
    do {                                                                                   \
        _Pragma("unroll") for (int q = 0; q < 8; ++q)                                      \
            ms[q] = *reinterpret_cast<const f32x4*>(                                       \
                Atw + (size_t)(q * 8 + sr) * K_DIM + (ksv) * 32 + sk * 4);                 \
    } while (0)

#define MF_WRITE(bufv)                                                                    \
    do {                                                                                   \
        _Pragma("unroll") for (int q = 0; q < 8; ++q) {                                    \
            uint2v o;                                                                      \
            o.x = pack2(ms[q].x, ms[q].y);                                                 \
            o.y = pack2(ms[q].z, ms[q].w);                                                 \
            int byte = sg * 1024 + (q * 8 + sr) * 16 + sh * 8;                             \
            byte ^= (sg << 4);                                                             \
            *reinterpret_cast<uint2v*>(wbase + (bufv) * 4096 + byte) = o;                  \
        }                                                                                  \
    } while (0)

#define AF_GLOAD(slot, ksv)                                                                \
    do {                                                                                   \
        _Pragma("unroll") for (int i = 0; i < 4; ++i)                                      \
            afr[slot][i] = *reinterpret_cast<const bf16x8*>(                               \
                Ct + (size_t)((ksv) * 4 + lg) * CHUNK_G_STRIDE                             \
                   + (size_t)(eb + we + i * 16 + l15) * 8);                                \
    } while (0)

    // prologue: fill buf0 + af slot0
    MF_GLOAD(0);
    AF_GLOAD(0, 0);
    MF_WRITE(0);

#pragma unroll
    for (int ks = 0; ks < 8; ++ks) {
        const int cur = ks & 1;
        if (ks < 7) { MF_GLOAD(ks + 1); AF_GLOAD(cur ^ 1, ks + 1); }   // issue-early

        bf16x8 mf[4];
#pragma unroll
        for (int j = 0; j < 4; ++j) {
            int byte = lg * 1024 + (j * 16 + l15) * 16;
            byte ^= (lg << 4);
            mf[j] = *reinterpret_cast<const bf16x8*>(wbase + cur * 4096 + byte);
        }
#pragma unroll
        for (int i = 0; i < 4; ++i)
#pragma unroll
            for (int j = 0; j < 4; ++j)
                acc[i][j] = __builtin_amdgcn_mfma_f32_16x16x32_bf16(afr[cur][i], mf[j], acc[i][j], 0, 0, 0);

        if (ks < 7) MF_WRITE(cur ^ 1);   // pack+write next buf (vmcnt wait folds here)
    }
#undef MF_GLOAD
#undef MF_WRITE
#undef AF_GLOAD

#pragma unroll
    for (int i = 0; i < 4; ++i) {
        int e0 = eb + we + i * 16 + lg * 4;   // 4 consecutive e -> float4 store
#pragma unroll
        for (int j = 0; j < 4; ++j) {
            int m = mb + wm + j * 16 + l15;
            *reinterpret_cast<f32x4*>(out + (size_t)t * (M_DIM * DENSE) + (size_t)m * DENSE + e0) = acc[i][j];
        }
    }
}

extern "C" void kernel_launch(void* const* d_in, const int* in_sizes, int n_in,
                              void* d_out, int out_size, void* d_ws, size_t ws_size,
                              hipStream_t stream) {
    const float* x_main = (const float*)d_in[0];   // [1,128,512,256]
    const float* x_aux  = (const float*)d_in[1];   // [256,128,256]
    const float* W      = (const float*)d_in[2];   // [256,512]
    const float* b      = (const float*)d_in[3];   // [512]
    float* out = (float*)d_out;                    // [1,128,512,512,1]

    // ws layout: Wc 256KiB @0 ; auxc 32MiB @ 1<<19. Total 32.5 MiB.
    unsigned short* Wc   = (unsigned short*)d_ws;
    unsigned short* auxc = (unsigned short*)((char*)d_ws + (1u << 19));

    wchunk_kernel<<<64, 256, 0, stream>>>(W, Wc);
    aux_kernel<<<1024, 256, 0, stream>>>(x_aux, Wc, b, auxc);
    main_kernel<<<2048, 256, 0, stream>>>(x_main, auxc, out);
}